// Round 7
// baseline (1072.928 us; speedup 1.0000x reference)
//
#include <hip/hip_runtime.h>

// EncoderLayer: B=8, D=512, S=4096, F=2048. fp32 in / fp32 out (proven R4).
// R8 @1022 (flash 505): Q64/K128 LDS-staged dbuf, 5 __syncthreads/kt.
// R9 @1241 FAILED: small tiles. R10 @1276 FAILED: K direct from L2.
// R11 @1035 (flash 514): stage-after-barrier + XCD swizzle: FETCH 278->82MB,
//   time unchanged. R12 @1084: qreg spill (VGPR capped 128). R13 @1033
//   (flash 514): half-qreg, -25% S1 LDS reads, time unchanged.
// Elimination: HBM, V-latency, prefetch order, occupancy, LDS volume all
//   NULL. Remaining structural cost (m233): every __syncthreads lowers to
//   vmcnt(0) -> the 32KB chunk staged ONE phase ago must fully land at
//   EVERY barrier (depth-1 dbuf). ~2-3k cy/phase exposed drain.
// R14 (T3/T4 port): Ks TRIPLE buffer, stage chunk m+2 at phase m (depth 2);
//   kc barriers = raw s_barrier with counted s_waitcnt vmcnt(4) (drains only
//   the 2-phase-old stage; newest stage stays in flight ACROSS barriers);
//   Ps barrier = lgkmcnt(0) only. Stages unconditional (tail reads spill
//   into V rows of same alloc: in-bounds, unused) so vmcnt(4) is always
//   exact. sched_barrier(0) fences per rule #18. LDS 150KB (Qs32+Ks96+
//   Ps17+rsL2), 1 blk/CU, VGPR ~120.

typedef unsigned short u16;
typedef __attribute__((ext_vector_type(4))) float f32x4;
typedef __attribute__((ext_vector_type(8))) short s16x8;

__device__ __forceinline__ float bf2f(u16 u) {
    unsigned int v = ((unsigned int)u) << 16;
    float f;
    __builtin_memcpy(&f, &v, 4);
    return f;
}
__device__ __forceinline__ u16 f2bf(float f) {
    unsigned int v;
    __builtin_memcpy(&v, &f, 4);
    unsigned int r = (v + 0x7fffu + ((v >> 16) & 1u)) >> 16;
    return (u16)r;
}
__device__ __forceinline__ u16 loadbf(const void* p, long long i, int f32) {
    return f32 ? f2bf(((const float*)p)[i]) : ((const u16*)p)[i];
}

#if defined(__has_builtin)
#if __has_builtin(__builtin_amdgcn_global_load_lds)
#define HAS_GLDS 1
#endif
#endif
#ifndef HAS_GLDS
#define HAS_GLDS 0
#endif

#if HAS_GLDS
__device__ __forceinline__ void glds16(const u16* g, u16* l) {
    __builtin_amdgcn_global_load_lds(
        (const __attribute__((address_space(1))) void*)g,
        (__attribute__((address_space(3))) void*)l, 16, 0, 0);
}
#else
__device__ __forceinline__ void glds16(const u16* g, u16* l) {
    *(int4*)l = *(const int4*)g;
}
#endif

// Counted-vmcnt barrier (T4): drain only loads older than the newest 4;
// the newest stage crosses the barrier in flight. sched_barrier fences
// stop hipcc hoisting MFMAs past the inline-asm wait (rule #18).
__device__ __forceinline__ void bar_vmcnt4() {
    asm volatile("s_waitcnt vmcnt(4)" ::: "memory");
    __builtin_amdgcn_sched_barrier(0);
    __builtin_amdgcn_s_barrier();
    __builtin_amdgcn_sched_barrier(0);
}
// LDS-visibility barrier (Ps writes) with NO vmcnt drain: in-flight
// global_load_lds stages pass through untouched.
__device__ __forceinline__ void bar_lds() {
    asm volatile("s_waitcnt lgkmcnt(0)" ::: "memory");
    __builtin_amdgcn_sched_barrier(0);
    __builtin_amdgcn_s_barrier();
    __builtin_amdgcn_sched_barrier(0);
}

// ---------------------------------------------------------------------------
// Input dtype detection (fp32 vs bf16) for all 9 inputs in ONE dispatch.
// ---------------------------------------------------------------------------
struct DetectArgs { const u16* p[9]; int n[9]; };

__global__ __launch_bounds__(256) void detect9(DetectArgs a, int* __restrict__ flags)
{
    const u16* p = a.p[blockIdx.x];
    const int n_u16 = a.n[blockIdx.x];
    int insane = 0;
    for (int i = threadIdx.x; i < n_u16; i += 256) {
        u16 h = p[i];
        int e = (h >> 7) & 0xFF;
        int m = h & 0x7F;
        bool sane = (e >= 96 && e <= 141) || (e == 0 && m == 0);
        insane += sane ? 0 : 1;
    }
#pragma unroll
    for (int off = 32; off > 0; off >>= 1) insane += __shfl_down(insane, off);
    __shared__ int red[4];
    if ((threadIdx.x & 63) == 0) red[threadIdx.x >> 6] = insane;
    __syncthreads();
    if (threadIdx.x == 0)
        flags[blockIdx.x] = (red[0] + red[1] + red[2] + red[3] > n_u16 / 4) ? 1 : 0;
}

// ---------------------------------------------------------------------------
// bf16 MFMA GEMM (R7 structure: dbuf glds + XOR k-chunk swizzle + XCD swizzle)
// ---------------------------------------------------------------------------
#define BM 128
#define BN 128
#define BK 32

template <typename OutT, bool BIAS, bool RELU>
__global__ __launch_bounds__(256) void gemm_bt(
    const u16* __restrict__ A, const u16* __restrict__ Bt, OutT* __restrict__ C,
    const u16* __restrict__ bias, int M, int N, int K,
    int lda, int ldb, int ldc, int wmod,
    long long aZ, long long aW, long long bZ, long long bW, long long cZ,
    int swz)
{
    __shared__ u16 As[2][BM * BK];
    __shared__ u16 Bs[2][BN * BK];

    const int z = blockIdx.z;
    const int g = z / wmod, w = z - g * wmod;
    A  += g * aZ + w * aW;
    Bt += g * bZ + w * bW;
    C  += (long long)z * cZ;

    int bx = blockIdx.x, by = blockIdx.y;
    if (swz) {
        const int gx = gridDim.x;
        int id = by * gx + bx;
        int xcd = id & 7, j = id >> 3;
        bx = j % gx;
        by = (j / gx) * 8 + xcd;
    }

    const int tid = threadIdx.x;
    const int wave = tid >> 6, lane = tid & 63;
    const int wm = wave >> 1, wn = wave & 1;
    const int q = lane >> 4, r = lane & 15;

    const int ar = tid >> 2;
    const int ac = (((tid & 3) ^ ((tid >> 3) & 3)) << 3);
    const int ks = (r >> 1) & 3;

    const u16* Ag = A + (long long)(by * BM + ar) * lda + ac;
    const u16* Bg = Bt + (long long)(bx * BN + ar) * ldb + ac;
    const long long rstepA = 64LL * lda, rstepB = 64LL * ldb;

    f32x4 acc[4][4];
    const f32x4 zero = {0.f, 0.f, 0.f, 0.f};
#pragma unroll
    for (int i = 0; i < 4; ++i)
#pragma unroll
        for (int j = 0; j < 4; ++j) acc[i][j] = zero;

    const int nIter = K / BK;
    glds16(Ag, &As[0][tid * 8]);
    glds16(Ag + rstepA, &As[0][2048 + tid * 8]);
    glds16(Bg, &Bs[0][tid * 8]);
    glds16(Bg + rstepB, &Bs[0][2048 + tid * 8]);
    Ag += BK; Bg += BK;
    __syncthreads();
    for (int it = 0; it < nIter; ++it) {
        const int cur = it & 1, nxt = cur ^ 1;
        if (it + 1 < nIter) {
            glds16(Ag, &As[nxt][tid * 8]);
            glds16(Ag + rstepA, &As[nxt][2048 + tid * 8]);
            glds16(Bg, &Bs[nxt][tid * 8]);
            glds16(Bg + rstepB, &Bs[nxt][2048 + tid * 8]);
            Ag += BK; Bg += BK;
        }
        s16x8 af[4], bf[4];
#pragma unroll
        for (int mi = 0; mi < 4; ++mi)
            af[mi] = *(const s16x8*)(&As[cur][(wm * 64 + mi * 16 + r) * BK + ((q ^ ks) << 3)]);
#pragma unroll
        for (int ni = 0; ni < 4; ++ni)
            bf[ni] = *(const s16x8*)(&Bs[cur][(wn * 64 + ni * 16 + r) * BK + ((q ^ ks) << 3)]);
#pragma unroll
        for (int mi = 0; mi < 4; ++mi)
#pragma unroll
            for (int ni = 0; ni < 4; ++ni)
                acc[mi][ni] = __builtin_amdgcn_mfma_f32_16x16x32_bf16(
                    af[mi], bf[ni], acc[mi][ni], 0, 0, 0);
        __syncthreads();
    }

    const int col0 = bx * BN + wn * 64;
    const int row0 = by * BM + wm * 64;
#pragma unroll
    for (int ni = 0; ni < 4; ++ni) {
        const int colg = col0 + ni * 16 + r;
        float bv = 0.f;
        if constexpr (BIAS) bv = bf2f(bias[colg]);
#pragma unroll
        for (int mi = 0; mi < 4; ++mi) {
#pragma unroll
            for (int rr = 0; rr < 4; ++rr) {
                const int rowg = row0 + mi * 16 + q * 4 + rr;
                float v = acc[mi][ni][rr] + bv;
                if constexpr (RELU) v = fmaxf(v, 0.f);
                if constexpr (sizeof(OutT) == 2)
                    C[(long long)rowg * ldc + colg] = (OutT)f2bf(v);
                else
                    C[(long long)rowg * ldc + colg] = (OutT)v;
            }
        }
    }
}

// ---------------------------------------------------------------------------
// Flash attention, R14. 512 thr / 8 waves; Q64 tile: K-steps 0-7 in regs
// (qreg[2][8]), steps 8-15 in 32KB Qs. K-tile 128 keys; chunks (128x128B)
// TRIPLE-buffered: chunk m read at phase m, staged at phase m-2, so every
// kc barrier drains only the 2-phase-old stage (vmcnt(4)) and the newest
// stage stays in flight. Ps barrier = lgkmcnt(0) only. V direct from global
// (XCD-swizzled L2-local). Stages unconditional -> uniform vmcnt counting.
// ---------------------------------------------------------------------------
template <bool DIRECT>
__global__ __launch_bounds__(512, 2) void flash_attn(
    const u16* __restrict__ QKV,   // [G][3][S*D]
    const u16* __restrict__ Vt,    // [G][D*S]
    u16* __restrict__ O,           // [G][S*D] bf16 (DIRECT)
    float* __restrict__ Opart,     // [G*ns][S*D] fp32 (!DIRECT)
    float* __restrict__ rsPart,    // [G*ns][S] fp32 (!DIRECT)
    int nsplit)
{
    __shared__ u16 Qs[64 * 256];       // 32 KB: K-dim upper half (elems 256..511)
    __shared__ u16 Ks[3][128 * 128];   // 3 x 32 KB, xor-swizzled (triple buffer)
    __shared__ u16 Ps[64 * 136];       // +8 pad per row (17 KB)
    __shared__ float rsL[8][64];

    const long long SD = 4096LL * 512;
    int g = blockIdx.z, qb = blockIdx.x;
    if (gridDim.z == 8 && gridDim.y == 1) {
        // XCD swizzle: id&7 constant per XCD => each XCD serves one batch
        // (K/V hot set resident in its 4MB L2; FETCH 278->82MB proven R11).
        int id = g * 64 + qb;
        g = id & 7; qb = id >> 3;
    }
    const int sp = blockIdx.y;
    const int q0 = qb * 64;
    const u16* Qg = QKV + ((long long)g * 3 + 0) * SD;
    const u16* Kg = QKV + ((long long)g * 3 + 1) * SD;
    const u16* Vg = Vt + (long long)g * SD;

    const int tid = threadIdx.x;
    const int wave = tid >> 6, lane = tid & 63;
    const int q = lane >> 4, r = lane & 15;
    const int mg = wave >> 2, ng = wave & 3;   // S1 roles (2 x 4)
    const int dg = wave;                       // PV role (d-range dg*64)

    const int span = 4096 / nsplit;
    const int kt0 = sp * span;
    const int ktN = span / 128;
    const float scale = 0.044194173824159216f;  // 1/sqrt(512)

    // ---- Q lower half -> registers FIRST (so compiler waits for these
    // don't drain the stage pipeline). qreg[mi][t]: rows (mg*2+mi)*16+r,
    // k-step t=0..7, elements (t*4+q)*8..+8.
    s16x8 qreg[2][8];
#pragma unroll
    for (int mi = 0; mi < 2; ++mi) {
        const long long row = q0 + (mg * 2 + mi) * 16 + r;
#pragma unroll
        for (int t = 0; t < 8; ++t)
            qreg[mi][t] = *(const s16x8*)(Qg + row * 512 + (t * 4 + q) * 8);
    }

    // ---- stage Qs upper half (once), pre-swizzled source, linear dest ----
#pragma unroll
    for (int i = 0; i < 4; ++i) {
        int c = i * 512 + tid;             // chunk 0..2047
        int row = c >> 5, p = c & 31;
        int l = p ^ (row & 15);
        glds16(Qg + (long long)(q0 + row) * 512 + 256 + l * 8, &Qs[c * 8]);
    }

    // Stage of global chunk c (c = kt*4+kc): rows kt0+(c>>2)*128, cols
    // (c&3)*128, into buffer c%3. UNCONDITIONAL: tail chunks (c >= ktN*4)
    // read rows past K's end into V rows of the same [G][3][S*D] alloc —
    // in-bounds, never read back. Keeps 8 ops outstanding at every barrier
    // so vmcnt(4) is always exactly "2-phase-old stage drained".
    auto stageK = [&](int c) {
#pragma unroll
        for (int i = 0; i < 4; ++i) {
            int L = i * 512 + tid;
            int row = L >> 4, p = L & 15;
            int l = p ^ (row & 15);
            glds16(Kg + (long long)(kt0 + (c >> 2) * 128 + row) * 512 + (c & 3) * 128 + l * 8,
                   &Ks[c % 3][L * 8]);
        }
    };
    stageK(0);
    stageK(1);
    // Outstanding now: 16 qreg + 4 Qs + 4 c0 + 4 c1. First bar_vmcnt4
    // drains qreg+Qs+c0, keeps c1 in flight.

    f32x4 oacc[4][4];
    const f32x4 zero = {0.f, 0.f, 0.f, 0.f};
#pragma unroll
    for (int i = 0; i < 4; ++i)
#pragma unroll
        for (int j = 0; j < 4; ++j) oacc[i][j] = zero;
    float rsum[2][4] = {{0.f, 0.f, 0.f, 0.f}, {0.f, 0.f, 0.f, 0.f}};

    for (int kt = 0; kt < ktN; ++kt) {
        // ---- S1 = Q * Ktile^T ----
        f32x4 sacc[2][2];
#pragma unroll
        for (int i = 0; i < 2; ++i)
#pragma unroll
            for (int j = 0; j < 2; ++j) sacc[i][j] = zero;

        // kc = 0,1: Q operand from registers
#pragma unroll
        for (int kc = 0; kc < 2; ++kc) {
            bar_vmcnt4();                    // chunk kt*4+kc landed; next stays in flight
            stageK(kt * 4 + kc + 2);         // depth-2 prefetch (lands 2 phases out)
            const u16* Kb = Ks[(kt * 4 + kc) % 3];
#pragma unroll
            for (int sc = 0; sc < 4; ++sc) {
                s16x8 bf[2];
#pragma unroll
                for (int ni = 0; ni < 2; ++ni) {
                    int row = (ng * 2 + ni) * 16 + r;
                    int l = sc * 4 + q;
                    bf[ni] = *(const s16x8*)&Kb[row * 128 + ((l ^ r) << 3)];
                }
#pragma unroll
                for (int mi = 0; mi < 2; ++mi)
#pragma unroll
                    for (int ni = 0; ni < 2; ++ni)
                        sacc[mi][ni] = __builtin_amdgcn_mfma_f32_16x16x32_bf16(
                            qreg[mi][kc * 4 + sc], bf[ni], sacc[mi][ni], 0, 0, 0);
            }
        }
        // kc = 2,3: Q operand from Qs (upper K-dim half)
#pragma unroll
        for (int kc = 2; kc < 4; ++kc) {
            bar_vmcnt4();
            stageK(kt * 4 + kc + 2);         // kc=2,3 stage next kt's c0,c1
            const u16* Kb = Ks[(kt * 4 + kc) % 3];
#pragma unroll
            for (int sc = 0; sc < 4; ++sc) {
                s16x8 af[2], bf[2];
#pragma unroll
                for (int mi = 0; mi < 2; ++mi) {
                    int row = (mg * 2 + mi) * 16 + r;
                    int l = (kc - 2) * 16 + sc * 4 + q;     // chunk in upper half
                    af[mi] = *(const s16x8*)&Qs[row * 256 + ((l ^ r) << 3)];
                }
#pragma unroll
                for (int ni = 0; ni < 2; ++ni) {
                    int row = (ng * 2 + ni) * 16 + r;
                    int l = sc * 4 + q;
                    bf[ni] = *(const s16x8*)&Kb[row * 128 + ((l ^ r) << 3)];
                }
#pragma unroll
                for (int mi = 0; mi < 2; ++mi)
#pragma unroll
                    for (int ni = 0; ni < 2; ++ni)
                        sacc[mi][ni] = __builtin_amdgcn_mfma_f32_16x16x32_bf16(
                            af[mi], bf[ni], sacc[mi][ni], 0, 0, 0);
            }
        }
        // ---- P = exp, write Ps, accumulate rowsums ----
        // (WAR vs PV(kt-1) Ps reads: 4 kc barriers have passed since.)
#pragma unroll
        for (int mi = 0; mi < 2; ++mi) {
#pragma unroll
            for (int ni = 0; ni < 2; ++ni) {
                int col = (ng * 2 + ni) * 16 + r;
#pragma unroll
                for (int rr = 0; rr < 4; ++rr) {
                    int row = (mg * 2 + mi) * 16 + q * 4 + rr;
                    float v = __expf(fminf(sacc[mi][ni][rr] * scale, 30.f));
                    Ps[row * 136 + col] = f2bf(v);
                    rsum[mi][rr] += v;
                }
            }
        }
        bar_lds();   // Ps visible to all waves; in-flight K stages untouched
        // ---- PV: O^T += Vt * P^T (wave d-range dg*64, all 64 q-cols) ----
        const long long vbase = (long long)(dg * 64 + r) * 4096 + kt0 + kt * 128;
#pragma unroll
        for (int kc = 0; kc < 4; ++kc) {
            s16x8 af[4], bf[4];
#pragma unroll
            for (int mi = 0; mi < 4; ++mi)
                af[mi] = *(const s16x8*)(Vg + vbase + (long long)mi * 16 * 4096
                                         + kc * 32 + q * 8);
#pragma unroll
            for (int ni = 0; ni < 4; ++ni)
                bf[ni] = *(const s16x8*)&Ps[(ni * 16 + r) * 136 + kc * 32 + q * 8];
            __builtin_amdgcn_s_setprio(1);
#pragma unroll
            for (int mi = 0; mi < 4; ++mi)
#pragma unroll
                for (int ni = 0; ni < 4; ++ni)
                    oacc[mi][ni] = __builtin_amdgcn_mfma_f32_16x16x32_bf16(
                        af[mi], bf[ni], oacc[mi][ni], 0, 0, 0);
            __builtin_amdgcn_s_setprio(0);
        }
    }

    // ---- finalize rowsums: reduce over the 16 r-lanes, publish per wave ----
#pragma unroll
    for (int mi = 0; mi < 2; ++mi)
#pragma unroll
        for (int rr = 0; rr < 4; ++rr) {
            float s = rsum[mi][rr];
#pragma unroll
            for (int m = 1; m < 16; m <<= 1) s += __shfl_xor(s, m);
            rsum[mi][rr] = s;
        }
    if (r == 0) {
#pragma unroll
        for (int mi = 0; mi < 2; ++mi)
#pragma unroll
            for (int rr = 0; rr < 4; ++rr)
                rsL[wave][(mg * 2 + mi) * 16 + q * 4 + rr] = rsum[mi][rr];
    }
    __syncthreads();   // full drain: tail stages + rsL visibility
    // rowsum(row) = sum over the 4 ng-waves of that row's mg half.

    if constexpr (DIRECT) {
        u16* Og = O + (long long)g * SD;
#pragma unroll
        for (int ni = 0; ni < 4; ++ni) {
            int qrow = ni * 16 + r;
            int wb = (qrow >> 5) * 4;
            float rs = rsL[wb][qrow] + rsL[wb + 1][qrow]
                     + rsL[wb + 2][qrow] + rsL[wb + 3][qrow];
            float inv = 1.f / rs;
#pragma unroll
            for (int mi = 0; mi < 4; ++mi) {
                int d = (dg * 4 + mi) * 16 + q * 4;
                ushort4 o4;
                o4.x = f2bf(oacc[mi][ni][0] * inv);
                o4.y = f2bf(oacc[mi][ni][1] * inv);
                o4.z = f2bf(oacc[mi][ni][2] * inv);
                o4.w = f2bf(oacc[mi][ni][3] * inv);
                *(ushort4*)&Og[(long long)(q0 + qrow) * 512 + d] = o4;
            }
        }
    } else {
        const int pb = g * nsplit + sp;
        float* Op = Opart + (long long)pb * SD;
#pragma unroll
        for (int ni = 0; ni < 4; ++ni) {
            int qrow = ni * 16 + r;
#pragma unroll
            for (int mi = 0; mi < 4; ++mi) {
                int d = (dg * 4 + mi) * 16 + q * 4;
                float4 o4;
                o4.x = oacc[mi][ni][0]; o4.y = oacc[mi][ni][1];
                o4.z = oacc[mi][ni][2]; o4.w = oacc[mi][ni][3];
                *(float4*)&Op[(long long)(q0 + qrow) * 512 + d] = o4;
            }
        }
        if (tid < 64) {
            int wb = (tid >> 5) * 4;
            rsPart[(long long)pb * 4096 + q0 + tid] =
                rsL[wb][tid] + rsL[wb + 1][tid] + rsL[wb + 2][tid] + rsL[wb + 3][tid];
        }
    }
}

// reduce partial O / rowsums -> bf16 O.  grid (1024, G)
__global__ __launch_bounds__(256) void reduce_flash(
    const float* __restrict__ Opart, const float* __restrict__ rsPart,
    u16* __restrict__ O, int ns)
{
    const long long SD = 4096LL * 512;
    const int g = blockIdx.y;
    u16* Og = O + (long long)g * SD;
    const int base = blockIdx.x * 2048;
#pragma unroll
    for (int it = 0; it < 8; ++it) {
        int i = base + it * 256 + threadIdx.x;
        int row = i >> 9;
        float s = 0.f, rs = 0.f;
        for (int sp = 0; sp < ns; ++sp) {
            s += Opart[(long long)(g * ns + sp) * SD + i];
            rs += rsPart[(long long)(g * ns + sp) * 4096 + row];
        }
        Og[i] = f2bf(s / rs);
    }
}

// ---------------------------------------------------------------------------
__global__ __launch_bounds__(256) void transpose_any(
    const void* __restrict__ in, u16* __restrict__ out, int R, int C,
    long long sIn, long long sOut, const int* __restrict__ flag)
{
    __shared__ u16 tile[32][33];
    const int f32 = *flag;
    const long long ib = (long long)blockIdx.z * sIn;
    u16* ob = out + (long long)blockIdx.z * sOut;
    const int c0 = blockIdx.x * 32, r0 = blockIdx.y * 32;
    const int tx = threadIdx.x, ty = threadIdx.y;
#pragma unroll
    for (int i = 0; i < 4; ++i) {
        int rr = ty + i * 8;
        tile[rr][tx] = loadbf(in, ib + (long long)(r0 + rr) * C + c0 + tx, f32);
    }
    __syncthreads();
#pragma unroll
    for (int i = 0; i < 4; ++i) {
        int cc = ty + i * 8;
        ob[(long long)(c0 + cc) * R + r0 + tx] = tile[tx][cc];
    }
}

__global__ __launch_bounds__(256) void transpose_b16(
    const u16* __restrict__ in, u16* __restrict__ out, int R, int C,
    long long sIn, long long sOut)
{
    __shared__ u16 tile[32][33];
    in += (long long)blockIdx.z * sIn;
    out += (long long)blockIdx.z * sOut;
    const int c0 = blockIdx.x * 32, r0 = blockIdx.y * 32;
    const int tx = threadIdx.x, ty = threadIdx.y;
#pragma unroll
    for (int i = 0; i < 4; ++i) {
        int rr = ty + i * 8;
        tile[rr][tx] = in[(long long)(r0 + rr) * C + c0 + tx];
    }
    __syncthreads();
#pragma unroll
    for (int i = 0; i < 4; ++i) {
        int cc = ty + i * 8;
        out[(long long)(c0 + cc) * R + r0 + tx] = tile[tx][cc];
    }
}

__global__ __launch_bounds__(256) void convert_bias(
    const void* __restrict__ b1, const void* __restrict__ b2,
    u16* __restrict__ ob, const int* __restrict__ f1, const int* __restrict__ f2)
{
    int i = blockIdx.x * 256 + threadIdx.x;
    if (i < 2048) ob[i] = loadbf(b1, i, *f1);
    else if (i < 2560) ob[i] = loadbf(b2, i - 2048, *f2);
}

// ---------------------------------------------------------------------------
// Norm helpers
// ---------------------------------------------------------------------------
__global__ __launch_bounds__(256) void stats_add_partial(
    const u16* __restrict__ A, const u16* __restrict__ Bv,
    float2* __restrict__ partial)
{
    const int b = blockIdx.y;
    const long long yb = (long long)b * (4096LL * 512);
    const int base = blockIdx.x * 2048;
    float s = 0.f, ss = 0.f;
#pragma unroll
    for (int it = 0; it < 8; ++it) {
        int i = base + it * 256 + threadIdx.x;
        float z = bf2f(A[yb + i]) + bf2f(Bv[yb + i]);
        s += z; ss += z * z;
    }
#pragma unroll
    for (int off = 32; off > 0; off >>= 1) {
        s += __shfl_down(s, off); ss += __shfl_down(ss, off);
    }
    __shared__ float red[8];
    int lane = threadIdx.x & 63, wave = threadIdx.x >> 6;
    if (lane == 0) { red[wave * 2] = s; red[wave * 2 + 1] = ss; }
    __syncthreads();
    if (threadIdx.x == 0) {
        for (int w = 1; w < 4; ++w) { s += red[w * 2]; ss += red[w * 2 + 1]; }
        partial[b * 1024 + blockIdx.x] = make_float2(s, ss);
    }
}

__global__ __launch_bounds__(256) void stats_finish(
    const float2* __restrict__ partial, float2* __restrict__ stats, float N)
{
    const int b = blockIdx.x;
    float s = 0.f, ss = 0.f;
    for (int i = threadIdx.x; i < 1024; i += 256) {
        float2 p = partial[b * 1024 + i];
        s += p.x; ss += p.y;
    }
#pragma unroll
    for (int off = 32; off > 0; off >>= 1) {
        s += __shfl_down(s, off); ss += __shfl_down(ss, off);
    }
    __shared__ float red[8];
    int lane = threadIdx.x & 63, wave = threadIdx.x >> 6;
    if (lane == 0) { red[wave * 2] = s; red[wave * 2 + 1] = ss; }
    __syncthreads();
    if (threadIdx.x == 0) {
        for (int w = 1; w < 4; ++w) { s += red[w * 2]; ss += red[w * 2 + 1]; }
        float mean = s / N;
        float l2 = sqrtf(fmaxf(ss - s * s / N, 0.f));
        stats[b] = make_float2(mean, 1.f / (l2 + 1e-7f));
    }
}

__global__ __launch_bounds__(256) void post_kernel(
    const u16* __restrict__ A, const u16* __restrict__ Bv,
    const float2* __restrict__ stats, u16* __restrict__ post)
{
    const int b = blockIdx.y;
    const float2 st = stats[b];
    const long long yb = (long long)b * (4096LL * 512);
    const int base = blockIdx.x * 2048;
#pragma unroll
    for (int it = 0; it < 8; ++it) {
        int i = base + it * 256 + threadIdx.x;
        float z = bf2f(A[yb + i]) + bf2f(Bv[yb + i]);
        post[yb + i] = f2bf((z - st.x) * st.y);
    }
}

__global__ __launch_bounds__(256) void final_kernel(
    const u16* __restrict__ P, const u16* __restrict__ G,
    const float2* __restrict__ stats, float* __restrict__ out)
{
    __shared__ float tile[32][33];
    const int b = blockIdx.z;
    const float2 st = stats[b];
    const long long bb = (long long)b * (4096LL * 512);
    const int s0 = blockIdx.x * 32, d0 = blockIdx.y * 32;
    const int tx = threadIdx.x, ty = threadIdx.y;
#pragma unroll
    for (int i = 0; i < 4; ++i) {
        int sl = ty + i * 8;
        long long idx = bb + (long long)(s0 + sl) * 512 + d0 + tx;
        tile[sl][tx] = bf2f(P[idx]) + bf2f(G[idx]);
    }
    __syncthreads();
#pragma unroll
    for (int i = 0; i < 4; ++i) {
        int dl = ty + i * 8;
        out[bb + (long long)(d0 + dl) * 4096 + s0 + tx] =
            (tile[tx][dl] - st.x) * st.y;
    }
}

// ---------------------------------------------------------------------------
extern "C" void kernel_launch(void* const* d_in, const int* in_sizes, int n_in,
                              void* d_out, int out_size, void* d_ws, size_t ws_size,
                              hipStream_t stream)
{
    (void)out_size;
    const void* x  = d_in[0];
    const void* Wq = d_in[1];
    const void* Wk = d_in[2];
    const void* Wv = d_in[3];
    const void* Wo = d_in[4];
    const void* W1 = d_in[5];
    const void* b1 = d_in[6];
    const void* W2 = d_in[7];
    const void* b2 = d_in[8];

    const int Bb = 8, D = 512, S = 4096, F = 2048;
    const long long SD = (long long)S * D;
    const long long DD = (long long)D * D;

    char* ws = (char*)d_ws;
    size_t off = 0;
    auto take = [&](size_t bytes) -> char* {
        char* p = ws + off;
        off += (bytes + 255) & ~(size_t)255;
        return p;
    };
    u16* xt   = (u16*)take((size_t)Bb * SD * 2);   // [B,S,D] 33.5 MB
    u16* WqT  = (u16*)take((size_t)DD * 2);
    u16* WkT  = (u16*)take((size_t)DD * 2);
    u16* WvT  = (u16*)take((size_t)DD * 2);
    u16* WoT  = (u16*)take((size_t)DD * 2);
    u16* W1T  = (u16*)take((size_t)D * F * 2);
    u16* W2T  = (u16*)take((size_t)D * F * 2);
    u16* bb   = (u16*)take(2560 * 2);
    u16* post = (u16*)take((size_t)Bb * SD * 2);   // 33.5 MB; Opart/Y overlay
    float2* npart  = (float2*)take(8 * 1024 * sizeof(float2));
    float2* stats1v = (float2*)take(256);
    float2* stats2v = (float2*)take(256);
    int* flags = (int*)take(16 * sizeof(int));
    float* rsPart = (float*)take(4 * 4096 * sizeof(float));

    // batch group size (marginal per-G = Q,K,V,Vt = 4*4.19 MB); ws>=124 MB => G>=2
    size_t remaining = ws_size > off ? ws_size - off : 0;
    const size_t perG = (size_t)4 * SD * 2 + 4096;
    int G = (remaining >= 8 * perG) ? 8 : (remaining >= 4 * perG) ? 4 : 2;
    int ns = (G >= 4) ? 1 : 2;  // grid blocks = 64*ns*G >= 256

    u16* attnBuf = (u16*)take((size_t)4 * G * SD * 2);  // [G][3][S,D] + [G][D,S]
    u16* QKVb = attnBuf;
    u16* Vtb  = attnBuf + (size_t)3 * G * SD;
    float* Opart = (float*)post;          // ns*G*SD fp32 = 33.5 MB max (ns*G<=4)
    u16* Oall = (u16*)d_out;              // [B,S,D] bf16 scratch in d_out
    u16* Y    = post;                     // Wo output (Opart dead); post in-place later
    u16* Hbuf = (u16*)d_out;              // FFN hidden half [4S,F]
    u16* Gbuf = attnBuf;                  // FFN out [B,S,D] (attn buffers dead)

    DetectArgs da;
    for (int i = 0; i < 9; ++i) {
        da.p[i] = (const u16*)d_in[i];
        da.n[i] = (i < n_in && in_sizes[i] < 8192) ? in_sizes[i] : 8192;
    }
    detect9<<<dim3(9), 256, 0, stream>>>(da, flags);

    dim3 tb(32, 8, 1);
    transpose_any<<<dim3(S / 32, D / 32, Bb), tb, 0, stream>>>(x, xt, D, S, SD, SD, flags + 0);
    transpose_any<<<dim3(16, 16, 1), tb, 0, stream>>>(Wq, WqT, D, D, 0, 0, flags + 1);
    transpose_any<<<dim3(16, 16, 1), tb, 0, stream>>>(Wk, WkT, D, D, 0, 0, flags + 2);
    transpose_any<<<dim3(16, 16, 1), tb, 0, stream>>>(Wv, WvT, D, D, 0, 0, flags + 3);
    transpose_any<<<dim3(16, 16, 1), tb, 0, stream>>>(Wo, WoT, D, D, 0, 0, flags + 4);
    transpose_any<<<dim3(F / 32, D / 32, 1), tb, 0, stream>>>(W1, W1T, D, F, 0, 0, flags + 5);
    transpose_any<<<dim3(D / 32, F / 32, 1), tb, 0, stream>>>(W2, W2T, F, D, 0, 0, flags + 7);
    convert_bias<<<10, 256, 0, stream>>>(b1, b2, bb, flags + 6, flags + 8);

    // ---- attention ----
    for (int b0 = 0; b0 < Bb; b0 += G) {
        gemm_bt<u16, false, false><<<dim3(D / 128, S / 128, 3 * G), 256, 0, stream>>>(
            xt + (long long)b0 * SD, WqT, QKVb, nullptr, S, D, D, D, D, D,
            3, SD, 0, 0, DD, SD, 1);
        transpose_b16<<<dim3(D / 32, S / 32, G), tb, 0, stream>>>(
            QKVb + 2 * SD, Vtb, S, D, 3 * SD, SD);
        if (ns == 1) {
            flash_attn<true><<<dim3(64, 1, G), 512, 0, stream>>>(
                QKVb, Vtb, Oall + (long long)b0 * SD, nullptr, nullptr, 1);
        } else {
            flash_attn<false><<<dim3(64, ns, G), 512, 0, stream>>>(
                QKVb, Vtb, nullptr, Opart, rsPart, ns);
            reduce_flash<<<dim3(1024, G), 256, 0, stream>>>(
                Opart, rsPart, Oall + (long long)b0 * SD, ns);
        }
    }

    // Y = O @ Wo (into post region; Opart dead)
    gemm_bt<u16, false, false><<<dim3(D / 128, (Bb * S) / 128, 1), 256, 0, stream>>>(
        Oall, WoT, Y, nullptr, Bb * S, D, D, D, D, D, 1, 0, 0, 0, 0, 0, 1);

    // post = norm(xt + Y)  (post written in-place over Y: per-element read-then-write)
    stats_add_partial<<<dim3(1024, Bb), 256, 0, stream>>>(xt, Y, npart);
    stats_finish<<<dim3(Bb), 256, 0, stream>>>(npart, stats1v, (float)SD);
    post_kernel<<<dim3(1024, Bb), 256, 0, stream>>>(xt, Y, stats1v, post);

    // FFN halves: H in d_out, G in attnBuf
    for (int h = 0; h < 2; ++h) {
        gemm_bt<u16, true, true><<<dim3(F / 128, (4 * S) / 128, 1), 256, 0, stream>>>(
            post + (long long)h * 4 * SD, W1T, Hbuf, bb, 4 * S, F, D, D, D, F,
            1, 0, 0, 0, 0, 0, 1);
        gemm_bt<u16, true, false><<<dim3(D / 128, (4 * S) / 128, 1), 256, 0, stream>>>(
            Hbuf, W2T, Gbuf + (long long)h * 4 * SD, bb + 2048, 4 * S, D, F, F, F, D,
            1, 0, 0, 0, 0, 0, 1);
    }

    // out = norm(post + G), transposed to [B,D,S], fp32
    stats_add_partial<<<dim3(1024, Bb), 256, 0, stream>>>(post, Gbuf, npart);
    stats_finish<<<dim3(Bb), 256, 0, stream>>>(npart, stats2v, (float)SD);
    final_kernel<<<dim3(S / 32, D / 32, Bb), tb, 0, stream>>>(
        post, Gbuf, stats2v, (float*)d_out);
}

// Round 8
// 1024.738 us; speedup vs baseline: 1.0470x; 1.0470x over previous
//
#include <hip/hip_runtime.h>

// EncoderLayer: B=8, D=512, S=4096, F=2048. fp32 in / fp32 out (proven R4).
// R8 @1022 (flash 505): Q64/K128 LDS dbuf, 8 waves, 5 barriers/kt.
// R9 @1241 FAILED small tiles. R10 @1276 FAILED K-direct. R11 @1035 (514):
//   stage-after-barrier + XCD swizzle (FETCH 278->82MB), null. R12 @1084
//   qreg spill. R13 @1033 (514): -25% S1 LDS reads, null. R14 @1073 (554):
//   counted vmcnt + depth-2 prefetch, slightly worse.
// Elimination: HBM, V-latency, prefetch order, tile-occupancy, LDS volume,
//   VGPR, barrier-drain ALL null. Floor ~250us vs measured 505: no pipe
//   saturated (Mfma 21 + VALU 15 + LDS ~27 << 100) -> intra-phase latency
//   exposure at 2 waves/SIMD (1x 8-wave block resident at 150KB LDS).
// R15: SAME tile/traffic/barriers, 16 waves (1024 thr) per block. S1 roles
//   mg(2) x ng(8) (1 key-frag/wave); PV dg 0..15 (d-range 32, oacc[2][4]);
//   VGPR ~105 fits the structural 128 cap (4 waves/SIMD). Q full-LDS.
//   R11 barrier/stage ordering (R14 machinery reverted). 2x latency hiding
//   at identical phase sizes.

typedef unsigned short u16;
typedef __attribute__((ext_vector_type(4))) float f32x4;
typedef __attribute__((ext_vector_type(8))) short s16x8;

__device__ __forceinline__ float bf2f(u16 u) {
    unsigned int v = ((unsigned int)u) << 16;
    float f;
    __builtin_memcpy(&f, &v, 4);
    return f;
}
__device__ __forceinline__ u16 f2bf(float f) {
    unsigned int v;
    __builtin_memcpy(&v, &f, 4);
    unsigned int r = (v + 0x7fffu + ((v >> 16) & 1u)) >> 16;
    return (u16)r;
}
__device__ __forceinline__ u16 loadbf(const void* p, long long i, int f32) {
    return f32 ? f2bf(((const float*)p)[i]) : ((const u16*)p)[i];
}

#if defined(__has_builtin)
#if __has_builtin(__builtin_amdgcn_global_load_lds)
#define HAS_GLDS 1
#endif
#endif
#ifndef HAS_GLDS
#define HAS_GLDS 0
#endif

#if HAS_GLDS
__device__ __forceinline__ void glds16(const u16* g, u16* l) {
    __builtin_amdgcn_global_load_lds(
        (const __attribute__((address_space(1))) void*)g,
        (__attribute__((address_space(3))) void*)l, 16, 0, 0);
}
#else
__device__ __forceinline__ void glds16(const u16* g, u16* l) {
    *(int4*)l = *(const int4*)g;
}
#endif

// ---------------------------------------------------------------------------
// Input dtype detection (fp32 vs bf16) for all 9 inputs in ONE dispatch.
// ---------------------------------------------------------------------------
struct DetectArgs { const u16* p[9]; int n[9]; };

__global__ __launch_bounds__(256) void detect9(DetectArgs a, int* __restrict__ flags)
{
    const u16* p = a.p[blockIdx.x];
    const int n_u16 = a.n[blockIdx.x];
    int insane = 0;
    for (int i = threadIdx.x; i < n_u16; i += 256) {
        u16 h = p[i];
        int e = (h >> 7) & 0xFF;
        int m = h & 0x7F;
        bool sane = (e >= 96 && e <= 141) || (e == 0 && m == 0);
        insane += sane ? 0 : 1;
    }
#pragma unroll
    for (int off = 32; off > 0; off >>= 1) insane += __shfl_down(insane, off);
    __shared__ int red[4];
    if ((threadIdx.x & 63) == 0) red[threadIdx.x >> 6] = insane;
    __syncthreads();
    if (threadIdx.x == 0)
        flags[blockIdx.x] = (red[0] + red[1] + red[2] + red[3] > n_u16 / 4) ? 1 : 0;
}

// ---------------------------------------------------------------------------
// bf16 MFMA GEMM (R7 structure: dbuf glds + XOR k-chunk swizzle + XCD swizzle)
// ---------------------------------------------------------------------------
#define BM 128
#define BN 128
#define BK 32

template <typename OutT, bool BIAS, bool RELU>
__global__ __launch_bounds__(256) void gemm_bt(
    const u16* __restrict__ A, const u16* __restrict__ Bt, OutT* __restrict__ C,
    const u16* __restrict__ bias, int M, int N, int K,
    int lda, int ldb, int ldc, int wmod,
    long long aZ, long long aW, long long bZ, long long bW, long long cZ,
    int swz)
{
    __shared__ u16 As[2][BM * BK];
    __shared__ u16 Bs[2][BN * BK];

    const int z = blockIdx.z;
    const int g = z / wmod, w = z - g * wmod;
    A  += g * aZ + w * aW;
    Bt += g * bZ + w * bW;
    C  += (long long)z * cZ;

    int bx = blockIdx.x, by = blockIdx.y;
    if (swz) {
        const int gx = gridDim.x;
        int id = by * gx + bx;
        int xcd = id & 7, j = id >> 3;
        bx = j % gx;
        by = (j / gx) * 8 + xcd;
    }

    const int tid = threadIdx.x;
    const int wave = tid >> 6, lane = tid & 63;
    const int wm = wave >> 1, wn = wave & 1;
    const int q = lane >> 4, r = lane & 15;

    const int ar = tid >> 2;
    const int ac = (((tid & 3) ^ ((tid >> 3) & 3)) << 3);
    const int ks = (r >> 1) & 3;

    const u16* Ag = A + (long long)(by * BM + ar) * lda + ac;
    const u16* Bg = Bt + (long long)(bx * BN + ar) * ldb + ac;
    const long long rstepA = 64LL * lda, rstepB = 64LL * ldb;

    f32x4 acc[4][4];
    const f32x4 zero = {0.f, 0.f, 0.f, 0.f};
#pragma unroll
    for (int i = 0; i < 4; ++i)
#pragma unroll
        for (int j = 0; j < 4; ++j) acc[i][j] = zero;

    const int nIter = K / BK;
    glds16(Ag, &As[0][tid * 8]);
    glds16(Ag + rstepA, &As[0][2048 + tid * 8]);
    glds16(Bg, &Bs[0][tid * 8]);
    glds16(Bg + rstepB, &Bs[0][2048 + tid * 8]);
    Ag += BK; Bg += BK;
    __syncthreads();
    for (int it = 0; it < nIter; ++it) {
        const int cur = it & 1, nxt = cur ^ 1;
        if (it + 1 < nIter) {
            glds16(Ag, &As[nxt][tid * 8]);
            glds16(Ag + rstepA, &As[nxt][2048 + tid * 8]);
            glds16(Bg, &Bs[nxt][tid * 8]);
            glds16(Bg + rstepB, &Bs[nxt][2048 + tid * 8]);
            Ag += BK; Bg += BK;
        }
        s16x8 af[4], bf[4];
#pragma unroll
        for (int mi = 0; mi < 4; ++mi)
            af[mi] = *(const s16x8*)(&As[cur][(wm * 64 + mi * 16 + r) * BK + ((q ^ ks) << 3)]);
#pragma unroll
        for (int ni = 0; ni < 4; ++ni)
            bf[ni] = *(const s16x8*)(&Bs[cur][(wn * 64 + ni * 16 + r) * BK + ((q ^ ks) << 3)]);
#pragma unroll
        for (int mi = 0; mi < 4; ++mi)
#pragma unroll
            for (int ni = 0; ni < 4; ++ni)
                acc[mi][ni] = __builtin_amdgcn_mfma_f32_16x16x32_bf16(
                    af[mi], bf[ni], acc[mi][ni], 0, 0, 0);
        __syncthreads();
    }

    const int col0 = bx * BN + wn * 64;
    const int row0 = by * BM + wm * 64;
#pragma unroll
    for (int ni = 0; ni < 4; ++ni) {
        const int colg = col0 + ni * 16 + r;
        float bv = 0.f;
        if constexpr (BIAS) bv = bf2f(bias[colg]);
#pragma unroll
        for (int mi = 0; mi < 4; ++mi) {
#pragma unroll
            for (int rr = 0; rr < 4; ++rr) {
                const int rowg = row0 + mi * 16 + q * 4 + rr;
                float v = acc[mi][ni][rr] + bv;
                if constexpr (RELU) v = fmaxf(v, 0.f);
                if constexpr (sizeof(OutT) == 2)
                    C[(long long)rowg * ldc + colg] = (OutT)f2bf(v);
                else
                    C[(long long)rowg * ldc + colg] = (OutT)v;
            }
        }
    }
}

// ---------------------------------------------------------------------------
// Flash attention, R15. Block: 1024 thr / 16 waves (4 waves/SIMD = 2x the
// R8-R14 latency hiding at IDENTICAL tile/traffic/barriers). Q-tile 64 rows
// (Qs 64KB); K-tile 128 keys chunk-staged (4 x 128x128, dbuf 2x32KB,
// stage-after-barrier). V direct from global (XCD-swizzled L2-local).
// S1 roles: mg(2) x ng(8) — wave computes 2 row-frags x 1 key-frag.
// PV: dg = wave (0..15), d-range dg*32, oacc[2][4]. 5 barriers/kt.
// LDS 149KB. VGPR ~105 (structural cap 128 at 4 waves/SIMD).
// ---------------------------------------------------------------------------
template <bool DIRECT>
__global__ __launch_bounds__(1024, 1) void flash_attn(
    const u16* __restrict__ QKV,   // [G][3][S*D]
    const u16* __restrict__ Vt,    // [G][D*S]
    u16* __restrict__ O,           // [G][S*D] bf16 (DIRECT)
    float* __restrict__ Opart,     // [G*ns][S*D] fp32 (!DIRECT)
    float* __restrict__ rsPart,    // [G*ns][S] fp32 (!DIRECT)
    int nsplit)
{
    __shared__ u16 Qs[64 * 512];       // 64 KB, xor-swizzled 16B chunks
    __shared__ u16 Ks[2][128 * 128];   // 2 x 32 KB, xor-swizzled
    __shared__ u16 Ps[64 * 136];       // +8 pad per row (17 KB)
    __shared__ float rsL[16][64];      // 4 KB

    const long long SD = 4096LL * 512;
    int g = blockIdx.z, qb = blockIdx.x;
    if (gridDim.z == 8 && gridDim.y == 1) {
        // XCD swizzle: id&7 constant per XCD => each XCD serves one batch
        // (K/V hot set resident in its 4MB L2; FETCH 278->82MB proven R11).
        int id = g * 64 + qb;
        g = id & 7; qb = id >> 3;
    }
    const int sp = blockIdx.y;
    const int q0 = qb * 64;
    const u16* Qg = QKV + ((long long)g * 3 + 0) * SD;
    const u16* Kg = QKV + ((long long)g * 3 + 1) * SD;
    const u16* Vg = Vt + (long long)g * SD;

    const int tid = threadIdx.x;
    const int wave = tid >> 6, lane = tid & 63;
    const int q = lane >> 4, r = lane & 15;
    const int mg = wave >> 3, ng = wave & 7;   // S1 roles (2 x 8)
    const int dg = wave;                       // PV role (d-range dg*32)

    // ---- stage Q tile (once), xor-swizzled chunks ----
#pragma unroll
    for (int i = 0; i < 4; ++i) {
        int L = i * 1024 + tid;
        int row = L >> 6, p = L & 63;
        int l = p ^ (row & 15);
        glds16(Qg + (long long)(q0 + row) * 512 + l * 8, &Qs[L * 8]);
    }

    f32x4 oacc[2][4];
    const f32x4 zero = {0.f, 0.f, 0.f, 0.f};
#pragma unroll
    for (int i = 0; i < 2; ++i)
#pragma unroll
        for (int j = 0; j < 4; ++j) oacc[i][j] = zero;
    float rsum[2][4] = {{0.f, 0.f, 0.f, 0.f}, {0.f, 0.f, 0.f, 0.f}};

    const int span = 4096 / nsplit;
    const int kt0 = sp * span;
    const int ktN = span / 128;
    const float scale = 0.044194173824159216f;  // 1/sqrt(512)

    auto stageK = [&](int ktile, int kc, int buf) {
#pragma unroll
        for (int i = 0; i < 2; ++i) {
            int L = i * 1024 + tid;
            int row = L >> 4, p = L & 15;
            int l = p ^ (row & 15);
            glds16(Kg + (long long)(kt0 + ktile * 128 + row) * 512 + kc * 128 + l * 8,
                   &Ks[buf][L * 8]);
        }
    };
    stageK(0, 0, 0);   // drained (with Qs) at the first kc barrier

    for (int kt = 0; kt < ktN; ++kt) {
        // ---- S1 = Q * Ktile^T (wave: rows mg*32..+31, keys ng*16..+15) ----
        f32x4 sacc[2];
        sacc[0] = zero; sacc[1] = zero;

        for (int kc = 0; kc < 4; ++kc) {
            __syncthreads();
            // chunk kc resident (staged one phase ago); other buf read-done.
            if (kc < 3) stageK(kt, kc + 1, (kc + 1) & 1);  // overlaps MFMAs
            const u16* Kb = Ks[kc & 1];
            const int krow = ng * 16 + r;
#pragma unroll
            for (int sc = 0; sc < 4; ++sc) {
                int lk = sc * 4 + q;
                s16x8 bf = *(const s16x8*)&Kb[krow * 128 + ((lk ^ r) << 3)];
#pragma unroll
                for (int mi = 0; mi < 2; ++mi) {
                    int row = mg * 32 + mi * 16 + r;
                    int l = kc * 16 + sc * 4 + q;          // logical chunk (full row 64)
                    s16x8 af = *(const s16x8*)&Qs[row * 512 + ((l ^ r) << 3)];
                    sacc[mi] = __builtin_amdgcn_mfma_f32_16x16x32_bf16(
                        af, bf, sacc[mi], 0, 0, 0);
                }
            }
        }
        // ---- P = exp, write Ps, accumulate rowsums ----
        // (WAR vs PV(kt-1) Ps reads satisfied by the 4 kc barriers above.)
        {
            int col = ng * 16 + r;
#pragma unroll
            for (int mi = 0; mi < 2; ++mi) {
#pragma unroll
                for (int rr = 0; rr < 4; ++rr) {
                    int row = mg * 32 + mi * 16 + q * 4 + rr;
                    float v = __expf(fminf(sacc[mi][rr] * scale, 30.f));
                    Ps[row * 136 + col] = f2bf(v);
                    rsum[mi][rr] += v;
                }
            }
        }
        __syncthreads();                          // Ps visible to all waves
        // Stage next kt's chunk0 now (buf0 read-done since kc=3 barrier);
        // load overlaps the whole PV phase, drained at next kc=0 barrier.
        if (kt + 1 < ktN) stageK(kt + 1, 0, 0);
        // ---- PV: O^T += Vt * P^T (wave d-range dg*32, all 64 q-cols) ----
        const long long vbase = (long long)(dg * 32 + r) * 4096 + kt0 + kt * 128;
#pragma unroll
        for (int kc = 0; kc < 4; ++kc) {
            s16x8 af[2], bf[4];
#pragma unroll
            for (int mi = 0; mi < 2; ++mi)
                af[mi] = *(const s16x8*)(Vg + vbase + (long long)mi * 16 * 4096
                                         + kc * 32 + q * 8);
#pragma unroll
            for (int ni = 0; ni < 4; ++ni)
                bf[ni] = *(const s16x8*)&Ps[(ni * 16 + r) * 136 + kc * 32 + q * 8];
            __builtin_amdgcn_s_setprio(1);
#pragma unroll
            for (int mi = 0; mi < 2; ++mi)
#pragma unroll
                for (int ni = 0; ni < 4; ++ni)
                    oacc[mi][ni] = __builtin_amdgcn_mfma_f32_16x16x32_bf16(
                        af[mi], bf[ni], oacc[mi][ni], 0, 0, 0);
            __builtin_amdgcn_s_setprio(0);
        }
    }

    // ---- finalize rowsums: reduce over the 16 r-lanes, publish per wave ----
#pragma unroll
    for (int mi = 0; mi < 2; ++mi)
#pragma unroll
        for (int rr = 0; rr < 4; ++rr) {
            float s = rsum[mi][rr];
#pragma unroll
            for (int m = 1; m < 16; m <<= 1) s += __shfl_xor(s, m);
            rsum[mi][rr] = s;
        }
    if (r == 0) {
#pragma unroll
        for (int mi = 0; mi < 2; ++mi)
#pragma unroll
            for (int rr = 0; rr < 4; ++rr)
                rsL[wave][mg * 32 + mi * 16 + q * 4 + rr] = rsum[mi][rr];
    }
    __syncthreads();
    // rowsum(row) = sum over the 8 ng-waves of that row's mg half.

    if constexpr (DIRECT) {
        u16* Og = O + (long long)g * SD;
#pragma unroll
        for (int ni = 0; ni < 4; ++ni) {
            int qrow = ni * 16 + r;
            int wb = (qrow >> 5) * 8;
            float rs = 0.f;
#pragma unroll
            for (int j = 0; j < 8; ++j) rs += rsL[wb + j][qrow];
            float inv = 1.f / rs;
#pragma unroll
            for (int mi = 0; mi < 2; ++mi) {
                int d = dg * 32 + mi * 16 + q * 4;
                ushort4 o4;
                o4.x = f2bf(oacc[mi][ni][0] * inv);
                o4.y = f2bf(oacc[mi][ni][1] * inv);
                o4.z = f2bf(oacc[mi][ni][2] * inv);
                o4.w = f2bf(oacc[mi][ni][3] * inv);
                *(ushort4*)&Og[(long long)(q0 + qrow) * 512 + d] = o4;
            }
        }
    } else {
        const int pb = g * nsplit + sp;
        float* Op = Opart + (long long)pb * SD;
#pragma unroll
        for (int ni = 0; ni < 4; ++ni) {
            int qrow = ni * 16 + r;
#pragma unroll
            for (int mi = 0; mi < 2; ++mi) {
                int d = dg * 32 + mi * 16 + q * 4;
                float4 o4;
                o4.x = oacc[mi][ni][0]; o4.y = oacc[mi][ni][1];
                o4.z = oacc[mi][ni][2]; o4.w = oacc[mi][ni][3];
                *(float4*)&Op[(long long)(q0 + qrow) * 512 + d] = o4;
            }
        }
        if (tid < 64) {
            int wb = (tid >> 5) * 8;
            float rs = 0.f;
#pragma unroll
            for (int j = 0; j < 8; ++j) rs += rsL[wb + j][tid];
            rsPart[(long long)pb * 4096 + q0 + tid] = rs;
        }
    }
}

// reduce partial O / rowsums -> bf16 O.  grid (1024, G)
__global__ __launch_bounds__(256) void reduce_flash(
    const float* __restrict__ Opart, const float* __restrict__ rsPart,
    u16* __restrict__ O, int ns)
{
    const long long SD = 4096LL * 512;
    const int g = blockIdx.y;
    u16* Og = O + (long long)g * SD;
    const int base = blockIdx.x * 2048;
#pragma unroll
    for (int it = 0; it < 8; ++it) {
        int i = base + it * 256 + threadIdx.x;
        int row = i >> 9;
        float s = 0.f, rs = 0.f;
        for (int sp = 0; sp < ns; ++sp) {
            s += Opart[(long long)(g * ns + sp) * SD + i];
            rs += rsPart[(long long)(g * ns + sp) * 4096 + row];
        }
        Og[i] = f2bf(s / rs);
    }
}

// ---------------------------------------------------------------------------
__global__ __launch_bounds__(256) void transpose_any(
    const void* __restrict__ in, u16* __restrict__ out, int R, int C,
    long long sIn, long long sOut, const int* __restrict__ flag)
{
    __shared__ u16 tile[32][33];
    const int f32 = *flag;
    const long long ib = (long long)blockIdx.z * sIn;
    u16* ob = out + (long long)blockIdx.z * sOut;
    const int c0 = blockIdx.x * 32, r0 = blockIdx.y * 32;
    const int tx = threadIdx.x, ty = threadIdx.y;
#pragma unroll
    for (int i = 0; i < 4; ++i) {
        int rr = ty + i * 8;
        tile[rr][tx] = loadbf(in, ib + (long long)(r0 + rr) * C + c0 + tx, f32);
    }
    __syncthreads();
#pragma unroll
    for (int i = 0; i < 4; ++i) {
        int cc = ty + i * 8;
        ob[(long long)(c0 + cc) * R + r0 + tx] = tile[tx][cc];
    }
}

__global__ __launch_bounds__(256) void transpose_b16(
    const u16* __restrict__ in, u16* __restrict__ out, int R, int C,
    long long sIn, long long sOut)
{
    __shared__ u16 tile[32][33];
    in += (long long)blockIdx.z * sIn;
    out += (long long)blockIdx.z * sOut;
    const int c0 = blockIdx.x * 32, r0 = blockIdx.y * 32;
    const int tx = threadIdx.x, ty = threadIdx.y;
#pragma unroll
    for (int i = 0; i < 4; ++i) {
        int rr = ty + i * 8;
        tile[rr][tx] = in[(long long)(r0 + rr) * C + c0 + tx];
    }
    __syncthreads();
#pragma unroll
    for (int i = 0; i < 4; ++i) {
        int cc = ty + i * 8;
        out[(long long)(c0 + cc) * R + r0 + tx] = tile[tx][cc];
    }
}

__global__ __launch_bounds__(256) void convert_bias(
    const void* __restrict__ b1, const void* __restrict__ b2,
    u16* __restrict__ ob, const int* __restrict__ f1, const int* __restrict__ f2)
{
    int i = blockIdx.x * 256 + threadIdx.x;
    if (i < 2048) ob[i] = loadbf(b1, i, *f1);
    else if (i < 2560) ob[i] = loadbf(b2, i - 2048, *f2);
}

// ---------------------------------------------------------------------------
// Norm helpers
// ---------------------------------------------------------------------------
__global__ __launch_bounds__(256) void stats_add_partial(
    const u16* __restrict__ A, const u16* __restrict__ Bv,
    float2* __restrict__ partial)
{
    const int b = blockIdx.y;
    const long long yb = (long long)b * (4096LL * 512);
    const int base = blockIdx.x * 2048;
    float s = 0.f, ss = 0.f;
#pragma unroll
    for (int it = 0; it < 8; ++it) {
        int i = base + it * 256 + threadIdx.x;
        float z = bf2f(A[yb + i]) + bf2f(Bv[yb + i]);
        s += z; ss += z * z;
    }
#pragma unroll
    for (int off = 32; off > 0; off >>= 1) {
        s += __shfl_down(s, off); ss += __shfl_down(ss, off);
    }
    __shared__ float red[8];
    int lane = threadIdx.x & 63, wave = threadIdx.x >> 6;
    if (lane == 0) { red[wave * 2] = s; red[wave * 2 + 1] = ss; }
    __syncthreads();
    if (threadIdx.x == 0) {
        for (int w = 1; w < 4; ++w) { s += red[w * 2]; ss += red[w * 2 + 1]; }
        partial[b * 1024 + blockIdx.x] = make_float2(s, ss);
    }
}

__global__ __launch_bounds__(256) void stats_finish(
    const float2* __restrict__ partial, float2* __restrict__ stats, float N)
{
    const int b = blockIdx.x;
    float s = 0.f, ss = 0.f;
    for (int i = threadIdx.x; i < 1024; i += 256) {
        float2 p = partial[b * 1024 + i];
        s += p.x; ss += p.y;
    }
#pragma unroll
    for (int off = 32; off > 0; off >>= 1) {
        s += __shfl_down(s, off); ss += __shfl_down(ss, off);
    }
    __shared__ float red[8];
    int lane = threadIdx.x & 63, wave = threadIdx.x >> 6;
    if (lane == 0) { red[wave * 2] = s; red[wave * 2 + 1] = ss; }
    __syncthreads();
    if (threadIdx.x == 0) {
        for (int w = 1; w < 4; ++w) { s += red[w * 2]; ss += red[w * 2 + 1]; }
        float mean = s / N;
        float l2 = sqrtf(fmaxf(ss - s * s / N, 0.f));
        stats[b] = make_float2(mean, 1.f / (l2 + 1e-7f));
    }
}

__global__ __launch_bounds__(256) void post_kernel(
    const u16* __restrict__ A, const u16* __restrict__ Bv,
    const float2* __restrict__ stats, u16* __restrict__ post)
{
    const int b = blockIdx.y;
    const float2 st = stats[b];
    const long long yb = (long long)b * (4096LL * 512);
    const int base = blockIdx.x * 2048;
#pragma unroll
    for (int it = 0; it < 8; ++it) {
        int i = base + it * 256 + threadIdx.x;
        float z = bf2f(A[yb + i]) + bf2f(Bv[yb + i]);
        post[yb + i] = f2bf((z - st.x) * st.y);
    }
}

__global__ __launch_bounds__(256) void final_kernel(
    const u16* __restrict__ P, const u16* __restrict__ G,
    const float2* __restrict__ stats, float* __restrict__ out)
{
    __shared__ float tile[32][33];
    const int b = blockIdx.z;
    const float2 st = stats[b];
    const long long bb = (long long)b * (4096LL * 512);
    const int s0 = blockIdx.x * 32, d0 = blockIdx.y * 32;
    const int tx = threadIdx.x, ty = threadIdx.y;
#pragma unroll
    for (int i = 0; i < 4; ++i) {
        int sl = ty + i * 8;
        long long idx = bb + (long long)(s0 + sl) * 512 + d0 + tx;
        tile[sl][tx] = bf2f(P[idx]) + bf2f(G[idx]);
    }
    __syncthreads();
#pragma unroll
    for (int i = 0; i < 4; ++i) {
        int dl = ty + i * 8;
        out[bb + (long long)(d0 + dl) * 4096 + s0 + tx] =
            (tile[tx][dl] - st.x) * st.y;
    }
}

// ---------------------------------------------------------------------------
extern "C" void kernel_launch(void* const* d_in, const int* in_sizes, int n_in,
                              void* d_out, int out_size, void* d_ws, size_t ws_size,
                              hipStream_t stream)
{
    (void)out_size;
    const void* x  = d_in[0];
    const void* Wq = d_in[1];
    const void* Wk = d_in[2];
    const void* Wv = d_in[3];
    const void* Wo = d_in[4];
    const void* W1 = d_in[5];
    const void* b1 = d_in[6];
    const void* W2 = d_in[7];
    const void* b2 = d_in[8];

    const int Bb = 8, D = 512, S = 4096, F = 2048;
    const long long SD = (long long)S * D;
    const long long DD = (long long)D * D;

    char* ws = (char*)d_ws;
    size_t off = 0;
    auto take = [&](size_t bytes) -> char* {
        char* p = ws + off;
        off += (bytes + 255) & ~(size_t)255;
        return p;
    };
    u16* xt   = (u16*)take((size_t)Bb * SD * 2);   // [B,S,D] 33.5 MB
    u16* WqT  = (u16*)take((size_t)DD * 2);
    u16* WkT  = (u16*)take((size_t)DD * 2);
    u16* WvT  = (u16*)take((size_t)DD * 2);
    u16* WoT  = (u16*)take((size_t)DD * 2);
    u16* W1T  = (u16*)take((size_t)D * F * 2);
    u16* W2T  = (u16*)take((size_t)D * F * 2);
    u16* bb   = (u16*)take(2560 * 2);
    u16* post = (u16*)take((size_t)Bb * SD * 2);   // 33.5 MB; Opart/Y overlay
    float2* npart  = (float2*)take(8 * 1024 * sizeof(float2));
    float2* stats1v = (float2*)take(256);
    float2* stats2v = (float2*)take(256);
    int* flags = (int*)take(16 * sizeof(int));
    float* rsPart = (float*)take(4 * 4096 * sizeof(float));

    // batch group size (marginal per-G = Q,K,V,Vt = 4*4.19 MB); ws>=124 MB => G>=2
    size_t remaining = ws_size > off ? ws_size - off : 0;
    const size_t perG = (size_t)4 * SD * 2 + 4096;
    int G = (remaining >= 8 * perG) ? 8 : (remaining >= 4 * perG) ? 4 : 2;
    int ns = (G >= 4) ? 1 : 2;  // grid blocks = 64*ns*G >= 256

    u16* attnBuf = (u16*)take((size_t)4 * G * SD * 2);  // [G][3][S,D] + [G][D,S]
    u16* QKVb = attnBuf;
    u16* Vtb  = attnBuf + (size_t)3 * G * SD;
    float* Opart = (float*)post;          // ns*G*SD fp32 = 33.5 MB max (ns*G<=4)
    u16* Oall = (u16*)d_out;              // [B,S,D] bf16 scratch in d_out
    u16* Y    = post;                     // Wo output (Opart dead); post in-place later
    u16* Hbuf = (u16*)d_out;              // FFN hidden half [4S,F]
    u16* Gbuf = attnBuf;                  // FFN out [B,S,D] (attn buffers dead)

    DetectArgs da;
    for (int i = 0; i < 9; ++i) {
        da.p[i] = (const u16*)d_in[i];
        da.n[i] = (i < n_in && in_sizes[i] < 8192) ? in_sizes[i] : 8192;
    }
    detect9<<<dim3(9), 256, 0, stream>>>(da, flags);

    dim3 tb(32, 8, 1);
    transpose_any<<<dim3(S / 32, D / 32, Bb), tb, 0, stream>>>(x, xt, D, S, SD, SD, flags + 0);
    transpose_any<<<dim3(16, 16, 1), tb, 0, stream>>>(Wq, WqT, D, D, 0, 0, flags + 1);
    transpose_any<<<dim3(16, 16, 1), tb, 0, stream>>>(Wk, WkT, D, D, 0, 0, flags + 2);
    transpose_any<<<dim3(16, 16, 1), tb, 0, stream>>>(Wv, WvT, D, D, 0, 0, flags + 3);
    transpose_any<<<dim3(16, 16, 1), tb, 0, stream>>>(Wo, WoT, D, D, 0, 0, flags + 4);
    transpose_any<<<dim3(F / 32, D / 32, 1), tb, 0, stream>>>(W1, W1T, D, F, 0, 0, flags + 5);
    transpose_any<<<dim3(D / 32, F / 32, 1), tb, 0, stream>>>(W2, W2T, F, D, 0, 0, flags + 7);
    convert_bias<<<10, 256, 0, stream>>>(b1, b2, bb, flags + 6, flags + 8);

    // ---- attention ----
    for (int b0 = 0; b0 < Bb; b0 += G) {
        gemm_bt<u16, false, false><<<dim3(D / 128, S / 128, 3 * G), 256, 0, stream>>>(
            xt + (long long)b0 * SD, WqT, QKVb, nullptr, S, D, D, D, D, D,
            3, SD, 0, 0, DD, SD, 1);
        transpose_b16<<<dim3(D / 32, S / 32, G), tb, 0, stream>>>(
            QKVb + 2 * SD, Vtb, S, D, 3 * SD, SD);
        if (ns == 1) {
            flash_attn<true><<<dim3(64, 1, G), 1024, 0, stream>>>(
                QKVb, Vtb, Oall + (long long)b0 * SD, nullptr, nullptr, 1);
        } else {
            flash_attn<false><<<dim3(64, ns, G), 1024, 0, stream>>>(
                QKVb, Vtb, nullptr, Opart, rsPart, ns);
            reduce_flash<<<dim3(1024, G), 256, 0, stream>>>(
                Opart, rsPart, Oall + (long long)b0 * SD, ns);
        }
    }

    // Y = O @ Wo (into post region; Opart dead)
    gemm_bt<u16, false, false><<<dim3(D / 128, (Bb * S) / 128, 1), 256, 0, stream>>>(
        Oall, WoT, Y, nullptr, Bb * S, D, D, D, D, D, 1, 0, 0, 0, 0, 0, 1);

    // post = norm(xt + Y)  (post written in-place over Y: per-element read-then-write)
    stats_add_partial<<<dim3(1024, Bb), 256, 0, stream>>>(xt, Y, npart);
    stats_finish<<<dim3(Bb), 256, 0, stream>>>(npart, stats1v, (float)SD);
    post_kernel<<<dim3(1024, Bb), 256, 0, stream>>>(xt, Y, stats1v, post);

    // FFN halves: H in d_out, G in attnBuf
    for (int h = 0; h < 2; ++h) {
        gemm_bt<u16, true, true><<<dim3(F / 128, (4 * S) / 128, 1), 256, 0, stream>>>(
            post + (long long)h * 4 * SD, W1T, Hbuf, bb, 4 * S, F, D, D, D, F,
            1, 0, 0, 0, 0, 0, 1);
        gemm_bt<u16, true, false><<<dim3(D / 128, (4 * S) / 128, 1), 256, 0, stream>>>(
            Hbuf, W2T, Gbuf + (long long)h * 4 * SD, bb + 2048, 4 * S, D, F, F, F, D,
            1, 0, 0, 0, 0, 0, 1);
    }

    // out = norm(post + G), transposed to [B,D,S], fp32
    stats_add_partial<<<dim3(1024, Bb), 256, 0, stream>>>(post, Gbuf, npart);
    stats_finish<<<dim3(Bb), 256, 0, stream>>>(npart, stats2v, (float)SD);
    final_kernel<<<dim3(S / 32, D / 32, Bb), tb, 0, stream>>>(
        post, Gbuf, stats2v, (float*)d_out);
}